// Round 2
// baseline (673.556 us; speedup 1.0000x reference)
//
#include <hip/hip_runtime.h>

// GaussianSmoother: out[b,n] = sum_t x[b,t,n] * w[t],  w = normalized Gaussian(T=2048, sigma=20)
// x: [B=64, T=2048, N=1024] f32  -> out: [B, N] f32
// HBM-read-bound: 512 MiB in, ~85 us roofline at 6.3 TB/s.
//
// R1 restructure: one block = one (b, t-split) -> streams a CONTIGUOUS 512 KiB
// region (128 rows x 4 KiB); every wave load is one 1 KiB contiguous segment.
// 1024 blocks (4/CU, 16 waves/CU). 16 partials per (b,n) reduced in phase 2.

#define B_DIM 64
#define T_DIM 2048
#define N_DIM 1024
#define SIGMA 20.0f

#define S_SPLIT 16                  // t-splits across blocks
#define R_STEPS (T_DIM / S_SPLIT)   // 128 rows per block
#define BLOCK 256                   // 256 threads x float4 = 1024 floats = one row

__global__ __launch_bounds__(BLOCK) void GaussianSmoother_phase1(
    const float* __restrict__ x, float4* __restrict__ part) {
  __shared__ float w[R_STEPS];      // unnormalized Gaussian slice for this t-split

  const int tid = threadIdx.x;
  const int b = blockIdx.x & (B_DIM - 1);   // 0..63
  const int s = blockIdx.x >> 6;            // 0..15
  const int t0 = s * R_STEPS;

  if (tid < R_STEPS) {
    float d = (float)(t0 + tid - T_DIM / 2) * (1.0f / SIGMA);
    w[tid] = expf(-0.5f * d * d);
  }
  __syncthreads();

  // block streams rows t0..t0+127 of batch b: contiguous 512 KiB
  const float4* px = (const float4*)x + ((size_t)b * T_DIM + t0) * (N_DIM / 4) + tid;

  float4 acc = make_float4(0.0f, 0.0f, 0.0f, 0.0f);
#pragma unroll 8
  for (int i = 0; i < R_STEPS; ++i) {
    float4 v = px[(size_t)i * (N_DIM / 4)];
    float wt = w[i];
    acc.x += wt * v.x;
    acc.y += wt * v.y;
    acc.z += wt * v.z;
    acc.w += wt * v.w;
  }

  // partials layout: [S_SPLIT][B][N/4] float4 (4 MiB), fully overwritten
  part[((size_t)s * B_DIM + b) * (N_DIM / 4) + tid] = acc;
}

__global__ __launch_bounds__(BLOCK) void GaussianSmoother_phase2(
    const float4* __restrict__ part, float4* __restrict__ out) {
  __shared__ float wavesum[BLOCK / 64];

  const int tid = threadIdx.x;

  // normalizer: sum of the full Gaussian over T
  float local = 0.0f;
#pragma unroll
  for (int t = tid; t < T_DIM; t += BLOCK) {
    float d = (float)(t - T_DIM / 2) * (1.0f / SIGMA);
    local += expf(-0.5f * d * d);
  }
#pragma unroll
  for (int off = 32; off > 0; off >>= 1) local += __shfl_down(local, off);
  if ((tid & 63) == 0) wavesum[tid >> 6] = local;
  __syncthreads();
  float s0 = 0.0f;
#pragma unroll
  for (int i = 0; i < BLOCK / 64; ++i) s0 += wavesum[i];
  const float inv = 1.0f / s0;

  // one block per batch; thread tid handles n = 4*tid..4*tid+3
  const int b = blockIdx.x;
  float4 acc = make_float4(0.0f, 0.0f, 0.0f, 0.0f);
#pragma unroll
  for (int s = 0; s < S_SPLIT; ++s) {
    float4 v = part[((size_t)s * B_DIM + b) * (N_DIM / 4) + tid];
    acc.x += v.x; acc.y += v.y; acc.z += v.z; acc.w += v.w;
  }
  acc.x *= inv; acc.y *= inv; acc.z *= inv; acc.w *= inv;
  out[(size_t)b * (N_DIM / 4) + tid] = acc;
}

extern "C" void kernel_launch(void* const* d_in, const int* in_sizes, int n_in,
                              void* d_out, int out_size, void* d_ws, size_t ws_size,
                              hipStream_t stream) {
  const float* x = (const float*)d_in[0];
  float* out = (float*)d_out;
  float4* part = (float4*)d_ws;   // needs 16*64*256*16 B = 4 MiB of scratch

  GaussianSmoother_phase1<<<dim3(B_DIM * S_SPLIT), BLOCK, 0, stream>>>(x, part);
  GaussianSmoother_phase2<<<dim3(B_DIM), BLOCK, 0, stream>>>(part, (float4*)out);
}

// Round 3
// 580.141 us; speedup vs baseline: 1.1610x; 1.1610x over previous
//
#include <hip/hip_runtime.h>

// GaussianSmoother: out[b,n] = sum_t x[b,t,n] * w[t],  w = normalized Gaussian(T=2048, sigma=20)
// x: [B=64, T=2048, N=1024] f32  -> out: [B, N] f32
//
// R3 key insight: sigma=20 => weights outside |t-1024| < 192 (9.6 sigma) are
// ~1e-20 relative; truncating the window to t in [832,1216) changes outputs by
// <1e-18 (threshold 1.3e-2) but cuts HBM reads 512 MiB -> 96 MiB.
// Normalizer still uses the FULL analytic Gaussian sum (matches reference).
//
// Block = (b, 32-row t-split): streams a contiguous 128 KiB. 768 blocks.
// Deterministic cross-block reduction via 3 MiB of d_ws partials in phase 2.

#define B_DIM 64
#define T_DIM 2048
#define N_DIM 1024
#define SIGMA 20.0f

#define T_LO 832                    // window start (center - 192)
#define T_WIN 384                   // window length (center +/- 192)
#define S_SPLIT 12                  // t-splits across blocks
#define R_STEPS (T_WIN / S_SPLIT)   // 32 rows per block
#define BLOCK 256                   // 256 threads x float4 = one 4 KiB row

__global__ __launch_bounds__(BLOCK) void GaussianSmoother_phase1(
    const float* __restrict__ x, float4* __restrict__ part) {
  __shared__ float w[R_STEPS];      // unnormalized Gaussian slice for this split

  const int tid = threadIdx.x;
  const int b = blockIdx.x & (B_DIM - 1);   // 0..63
  const int s = blockIdx.x >> 6;            // 0..11
  const int t0 = T_LO + s * R_STEPS;

  if (tid < R_STEPS) {
    float d = (float)(t0 + tid - T_DIM / 2) * (1.0f / SIGMA);
    w[tid] = expf(-0.5f * d * d);
  }
  __syncthreads();

  // block streams rows t0..t0+31 of batch b: contiguous 128 KiB
  const float4* px = (const float4*)x + ((size_t)b * T_DIM + t0) * (N_DIM / 4) + tid;

  float4 acc = make_float4(0.0f, 0.0f, 0.0f, 0.0f);
#pragma unroll 8
  for (int i = 0; i < R_STEPS; ++i) {
    float4 v = px[(size_t)i * (N_DIM / 4)];
    float wt = w[i];
    acc.x += wt * v.x;
    acc.y += wt * v.y;
    acc.z += wt * v.z;
    acc.w += wt * v.w;
  }

  // partials layout: [S_SPLIT][B][N/4] float4 (3 MiB), fully overwritten
  part[((size_t)s * B_DIM + b) * (N_DIM / 4) + tid] = acc;
}

__global__ __launch_bounds__(BLOCK) void GaussianSmoother_phase2(
    const float4* __restrict__ part, float4* __restrict__ out) {
  __shared__ float wavesum[BLOCK / 64];

  const int tid = threadIdx.x;

  // normalizer: sum of the full Gaussian over ALL T (matches reference exactly)
  float local = 0.0f;
#pragma unroll
  for (int t = tid; t < T_DIM; t += BLOCK) {
    float d = (float)(t - T_DIM / 2) * (1.0f / SIGMA);
    local += expf(-0.5f * d * d);
  }
#pragma unroll
  for (int off = 32; off > 0; off >>= 1) local += __shfl_down(local, off);
  if ((tid & 63) == 0) wavesum[tid >> 6] = local;
  __syncthreads();
  float s0 = 0.0f;
#pragma unroll
  for (int i = 0; i < BLOCK / 64; ++i) s0 += wavesum[i];
  const float inv = 1.0f / s0;

  // one block per batch; thread tid handles n = 4*tid..4*tid+3
  const int b = blockIdx.x;
  float4 acc = make_float4(0.0f, 0.0f, 0.0f, 0.0f);
#pragma unroll
  for (int s = 0; s < S_SPLIT; ++s) {
    float4 v = part[((size_t)s * B_DIM + b) * (N_DIM / 4) + tid];
    acc.x += v.x; acc.y += v.y; acc.z += v.z; acc.w += v.w;
  }
  acc.x *= inv; acc.y *= inv; acc.z *= inv; acc.w *= inv;
  out[(size_t)b * (N_DIM / 4) + tid] = acc;
}

extern "C" void kernel_launch(void* const* d_in, const int* in_sizes, int n_in,
                              void* d_out, int out_size, void* d_ws, size_t ws_size,
                              hipStream_t stream) {
  const float* x = (const float*)d_in[0];
  float* out = (float*)d_out;
  float4* part = (float4*)d_ws;   // needs 12*64*256*16 B = 3 MiB of scratch

  GaussianSmoother_phase1<<<dim3(B_DIM * S_SPLIT), BLOCK, 0, stream>>>(x, part);
  GaussianSmoother_phase2<<<dim3(B_DIM), BLOCK, 0, stream>>>(part, (float4*)out);
}